// Round 1
// baseline (94.636 us; speedup 1.0000x reference)
//
#include <hip/hip_runtime.h>
#include <math.h>

#define BATCH 8192
#define NF 256
#define NH 64

__global__ __launch_bounds__(256) void mlp_per_sample(
    const float* __restrict__ x,
    const int*   __restrict__ task_ids,
    const float* __restrict__ l1_emb,   // [T, 256*64] row-major [f][h]
    const float* __restrict__ l2_emb,   // [T, 64*64]  row-major [h][k]
    const float* __restrict__ l3_emb,   // [T, 64]
    float*       __restrict__ out)      // [B]
{
    const int b   = blockIdx.x;
    const int tid = threadIdx.x;

    __shared__ float xs[NF];
    __shared__ float partial[4][NH];
    __shared__ float h1s[NH];
    __shared__ float h2s[NH];

    const int t = task_ids[b];

    // stage x row (256 floats, one per thread)
    xs[tid] = x[(size_t)b * NF + tid];
    __syncthreads();

    const int h = tid & 63;   // output column
    const int w = tid >> 6;   // wave id 0..3

    // ---- layer 1: h1 = gelu(x @ L1), L1[f][h] at t*16384 + f*64 + h ----
    {
        const float* L1 = l1_emb + (size_t)t * (NF * NH);
        float acc = 0.f;
        #pragma unroll 8
        for (int j = 0; j < 64; ++j) {
            const int f = w * 64 + j;
            acc += xs[f] * L1[(size_t)f * NH + h];   // lanes h=0..63 -> coalesced 256B
        }
        partial[w][h] = acc;
    }
    __syncthreads();
    if (tid < NH) {
        float s = partial[0][tid] + partial[1][tid] + partial[2][tid] + partial[3][tid];
        h1s[tid] = 0.5f * s * (1.f + erff(s * 0.70710678118654752440f)); // exact gelu
    }
    __syncthreads();

    // ---- layer 2: h2 = gelu(h1 @ L2), L2[h][k] at t*4096 + h*64 + k ----
    {
        const float* L2 = l2_emb + (size_t)t * (NH * NH);
        float acc = 0.f;
        #pragma unroll
        for (int j = 0; j < 16; ++j) {
            const int hh = w * 16 + j;
            acc += h1s[hh] * L2[(size_t)hh * NH + h];
        }
        partial[w][h] = acc;
    }
    __syncthreads();
    if (tid < NH) {
        float s = partial[0][tid] + partial[1][tid] + partial[2][tid] + partial[3][tid];
        h2s[tid] = 0.5f * s * (1.f + erff(s * 0.70710678118654752440f));
    }
    __syncthreads();

    // ---- layer 3: out = sigmoid(dot(h2, L3[t])) — wave 0 only ----
    if (tid < 64) {
        float v = h2s[tid] * l3_emb[(size_t)t * NH + tid];
        #pragma unroll
        for (int off = 32; off > 0; off >>= 1)
            v += __shfl_down(v, off);
        if (tid == 0)
            out[b] = 1.f / (1.f + expf(-v));
    }
}

extern "C" void kernel_launch(void* const* d_in, const int* in_sizes, int n_in,
                              void* d_out, int out_size, void* d_ws, size_t ws_size,
                              hipStream_t stream) {
    const float* x        = (const float*)d_in[0];
    const int*   task_ids = (const int*)  d_in[1];
    const float* l1_emb   = (const float*)d_in[2];
    const float* l2_emb   = (const float*)d_in[3];
    const float* l3_emb   = (const float*)d_in[4];
    float*       out      = (float*)d_out;

    mlp_per_sample<<<BATCH, 256, 0, stream>>>(x, task_ids, l1_emb, l2_emb, l3_emb, out);
}

// Round 2
// 58.760 us; speedup vs baseline: 1.6106x; 1.6106x over previous
//
#include <hip/hip_runtime.h>
#include <math.h>

#define BATCH 8192
#define NTASK 1024
#define NF 256
#define NH 64

// d_ws layout (ints): [0,1024) counts | [1024,2048) offsets | [2048,3072) cursor
//                     | [3072,3072+8192) order   => 45 KB total

__global__ __launch_bounds__(256) void zero_counts(int* counts, int* cursor) {
    int i = blockIdx.x * 256 + threadIdx.x;
    if (i < NTASK) { counts[i] = 0; cursor[i] = 0; }
}

__global__ __launch_bounds__(256) void hist_kernel(const int* __restrict__ task_ids,
                                                   int* __restrict__ counts) {
    int i = blockIdx.x * 256 + threadIdx.x;
    if (i < BATCH) atomicAdd(&counts[task_ids[i]], 1);
}

__global__ __launch_bounds__(1024) void scan1024(const int* __restrict__ counts,
                                                 int* __restrict__ offsets) {
    __shared__ int tmp[NTASK];
    int tid = threadIdx.x;
    int v = counts[tid];
    tmp[tid] = v;
    __syncthreads();
    for (int d = 1; d < NTASK; d <<= 1) {
        int t_ = (tid >= d) ? tmp[tid - d] : 0;
        __syncthreads();
        if (tid >= d) tmp[tid] += t_;
        __syncthreads();
    }
    offsets[tid] = tmp[tid] - v;  // exclusive prefix sum
}

__global__ __launch_bounds__(256) void scatter_kernel(const int* __restrict__ task_ids,
                                                      const int* __restrict__ offsets,
                                                      int* __restrict__ cursor,
                                                      int* __restrict__ order) {
    int i = blockIdx.x * 256 + threadIdx.x;
    if (i < BATCH) {
        int t = task_ids[i];
        int pos = atomicAdd(&cursor[t], 1);
        order[offsets[t] + pos] = i;
    }
}

__device__ __forceinline__ float gelu_exact(float s) {
    return 0.5f * s * (1.f + erff(s * 0.70710678118654752440f));
}

// one block per task; chunks of 8 samples; wave w handles samples 2w, 2w+1
__global__ __launch_bounds__(256) void mlp_task(
    const float* __restrict__ x,
    const int*   __restrict__ order,
    const int*   __restrict__ counts,
    const int*   __restrict__ offsets,
    const float* __restrict__ l1_emb,
    const float* __restrict__ l2_emb,
    const float* __restrict__ l3_emb,
    float*       __restrict__ out)
{
    const int t = blockIdx.x;
    const int cnt = counts[t];
    if (cnt == 0) return;
    const int base = offsets[t];
    const int tid = threadIdx.x;
    const int h = tid & 63;
    const int w = tid >> 6;

    __shared__ float xs[8][NF];
    __shared__ float h1s[8][NH];
    __shared__ int sidx[8];

    const float* L1 = l1_emb + (size_t)t * (NF * NH);
    const float* L2 = l2_emb + (size_t)t * (NH * NH);
    const float  l3v = l3_emb[(size_t)t * NH + h];

    for (int c0 = 0; c0 < cnt; c0 += 8) {
        const int S = min(8, cnt - c0);
        __syncthreads();                       // prev chunk done with xs/h1s/sidx
        if (tid < 8) sidx[tid] = (tid < S) ? order[base + c0 + tid] : 0;
        __syncthreads();
        #pragma unroll
        for (int s = 0; s < 8; ++s)
            xs[s][tid] = (s < S) ? x[(size_t)sidx[s] * NF + tid] : 0.f;
        __syncthreads();

        const int s0 = 2 * w, s1 = 2 * w + 1;

        // ---- layer 1: full f-reduction per thread, weight read once per wave ----
        float acc0 = 0.f, acc1 = 0.f;
        #pragma unroll 8
        for (int f = 0; f < NF; ++f) {
            float wv = L1[f * NH + h];         // 64 lanes -> coalesced 256B
            acc0 = fmaf(xs[s0][f], wv, acc0);
            acc1 = fmaf(xs[s1][f], wv, acc1);
        }
        h1s[s0][h] = gelu_exact(acc0);
        h1s[s1][h] = gelu_exact(acc1);
        __syncthreads();

        // ---- layer 2 ----
        acc0 = 0.f; acc1 = 0.f;
        #pragma unroll 8
        for (int hh = 0; hh < NH; ++hh) {
            float wv = L2[hh * NH + h];
            acc0 = fmaf(h1s[s0][hh], wv, acc0);
            acc1 = fmaf(h1s[s1][hh], wv, acc1);
        }
        float v0 = gelu_exact(acc0) * l3v;
        float v1 = gelu_exact(acc1) * l3v;

        // ---- layer 3: wave-wide dot reduce ----
        #pragma unroll
        for (int off = 32; off > 0; off >>= 1) {
            v0 += __shfl_down(v0, off);
            v1 += __shfl_down(v1, off);
        }
        if (h == 0) {
            if (s0 < S) out[sidx[s0]] = 1.f / (1.f + expf(-v0));
            if (s1 < S) out[sidx[s1]] = 1.f / (1.f + expf(-v1));
        }
    }
}

extern "C" void kernel_launch(void* const* d_in, const int* in_sizes, int n_in,
                              void* d_out, int out_size, void* d_ws, size_t ws_size,
                              hipStream_t stream) {
    const float* x        = (const float*)d_in[0];
    const int*   task_ids = (const int*)  d_in[1];
    const float* l1_emb   = (const float*)d_in[2];
    const float* l2_emb   = (const float*)d_in[3];
    const float* l3_emb   = (const float*)d_in[4];
    float*       out      = (float*)d_out;

    int* ws      = (int*)d_ws;
    int* counts  = ws;
    int* offsets = ws + 1024;
    int* cursor  = ws + 2048;
    int* order   = ws + 3072;

    zero_counts   <<<4, 256, 0, stream>>>(counts, cursor);
    hist_kernel   <<<BATCH / 256, 256, 0, stream>>>(task_ids, counts);
    scan1024      <<<1, 1024, 0, stream>>>(counts, offsets);
    scatter_kernel<<<BATCH / 256, 256, 0, stream>>>(task_ids, offsets, cursor, order);
    mlp_task      <<<NTASK, 256, 0, stream>>>(x, order, counts, offsets,
                                              l1_emb, l2_emb, l3_emb, out);
}

// Round 3
// 51.336 us; speedup vs baseline: 1.8434x; 1.1446x over previous
//
#include <hip/hip_runtime.h>
#include <math.h>

#define BATCH 8192
#define NTASK 1024
#define NF 256
#define NH 64

// d_ws layout (ints): [0,1024) counts | [1024,2048) offsets | [2048,3072) cursor
//                     | [3072,3072+8192) order   => 45 KB total

__global__ __launch_bounds__(256) void zero_counts(int* counts, int* cursor) {
    int i = blockIdx.x * 256 + threadIdx.x;
    if (i < NTASK) { counts[i] = 0; cursor[i] = 0; }
}

__global__ __launch_bounds__(256) void hist_kernel(const int* __restrict__ task_ids,
                                                   int* __restrict__ counts) {
    int i = blockIdx.x * 256 + threadIdx.x;
    if (i < BATCH) atomicAdd(&counts[task_ids[i]], 1);
}

__global__ __launch_bounds__(1024) void scan1024(const int* __restrict__ counts,
                                                 int* __restrict__ offsets) {
    __shared__ int tmp[NTASK];
    int tid = threadIdx.x;
    int v = counts[tid];
    tmp[tid] = v;
    __syncthreads();
    for (int d = 1; d < NTASK; d <<= 1) {
        int t_ = (tid >= d) ? tmp[tid - d] : 0;
        __syncthreads();
        if (tid >= d) tmp[tid] += t_;
        __syncthreads();
    }
    offsets[tid] = tmp[tid] - v;  // exclusive prefix sum
}

__global__ __launch_bounds__(256) void scatter_kernel(const int* __restrict__ task_ids,
                                                      const int* __restrict__ offsets,
                                                      int* __restrict__ cursor,
                                                      int* __restrict__ order) {
    int i = blockIdx.x * 256 + threadIdx.x;
    if (i < BATCH) {
        int t = task_ids[i];
        int pos = atomicAdd(&cursor[t], 1);
        order[offsets[t] + pos] = i;
    }
}

__device__ __forceinline__ float gelu_exact(float s) {
    return 0.5f * s * (1.f + erff(s * 0.70710678118654752440f));
}

__device__ __forceinline__ float4 gelu4(float4 v) {
    return make_float4(gelu_exact(v.x), gelu_exact(v.y), gelu_exact(v.z), gelu_exact(v.w));
}

// one block per task; chunks of 8 samples.
// thread = (grp = tid>>4, c = tid&15): grp is the reduction-slice group,
// c is the output column-quad (owns columns 4c..4c+3 as float4).
__global__ __launch_bounds__(256) void mlp_task(
    const float* __restrict__ x,
    const int*   __restrict__ order,
    const int*   __restrict__ counts,
    const int*   __restrict__ offsets,
    const float* __restrict__ l1_emb,
    const float* __restrict__ l2_emb,
    const float* __restrict__ l3_emb,
    float*       __restrict__ out)
{
    const int t = blockIdx.x;
    const int cnt = counts[t];
    if (cnt == 0) return;
    const int base = offsets[t];
    const int tid = threadIdx.x;
    const int wv  = tid >> 6;   // wave 0..3
    const int c   = tid & 15;   // column-quad
    const int grp = tid >> 4;   // slice group 0..15 (block-wide)

    __shared__ float  xs[8][NF];        // 8 KB
    __shared__ float4 red[4][8][17];    // wave x sample x (16 quads + pad) : 8.7 KB
    __shared__ float  h1s[8][NH];       // 2 KB
    __shared__ int    sidx[8];

    const float4* L1 = (const float4*)(l1_emb + (size_t)t * (NF * NH)); // [256][16]
    const float4* L2 = (const float4*)(l2_emb + (size_t)t * (NH * NH)); // [64][16]
    const float4* L3 = (const float4*)(l3_emb + (size_t)t * NH);        // [16]
    const float4* x4 = (const float4*)x;                                 // [B][64]

    for (int c0 = 0; c0 < cnt; c0 += 8) {
        const int S = min(8, cnt - c0);
        __syncthreads();                 // prev chunk done with xs/h1s/red
        if (tid < 8) sidx[tid] = (tid < S) ? order[base + c0 + tid] : 0;
        __syncthreads();

        // stage x: 8 samples x 64 float4 = 512 loads, 2 per thread
        #pragma unroll
        for (int i = 0; i < 2; ++i) {
            int idx = tid + i * 256;
            int s  = idx >> 6;
            int cc = idx & 63;
            float4 v = (s < S) ? x4[(size_t)sidx[s] * 64 + cc]
                               : make_float4(0.f, 0.f, 0.f, 0.f);
            ((float4*)xs)[s * 64 + cc] = v;
        }
        __syncthreads();

        // ---- layer 1: each thread reduces 16 f-rows, 4 cols, 8 samples ----
        float4 acc[8];
        #pragma unroll
        for (int s = 0; s < 8; ++s) acc[s] = make_float4(0.f, 0.f, 0.f, 0.f);
        #pragma unroll
        for (int j = 0; j < 16; ++j) {
            const int f = grp * 16 + j;
            float4 wv4 = L1[f * 16 + c];          // wave reads 1KB contiguous
            #pragma unroll
            for (int s = 0; s < 8; ++s) {
                float xv = xs[s][f];
                acc[s].x = fmaf(xv, wv4.x, acc[s].x);
                acc[s].y = fmaf(xv, wv4.y, acc[s].y);
                acc[s].z = fmaf(xv, wv4.z, acc[s].z);
                acc[s].w = fmaf(xv, wv4.w, acc[s].w);
            }
        }
        // reduce the 4 in-wave slice groups (lanes differ in bits 4,5)
        #pragma unroll
        for (int s = 0; s < 8; ++s) {
            acc[s].x += __shfl_xor(acc[s].x, 16); acc[s].y += __shfl_xor(acc[s].y, 16);
            acc[s].z += __shfl_xor(acc[s].z, 16); acc[s].w += __shfl_xor(acc[s].w, 16);
            acc[s].x += __shfl_xor(acc[s].x, 32); acc[s].y += __shfl_xor(acc[s].y, 32);
            acc[s].z += __shfl_xor(acc[s].z, 32); acc[s].w += __shfl_xor(acc[s].w, 32);
        }
        if ((tid & 63) < 16) {
            #pragma unroll
            for (int s = 0; s < 8; ++s) red[wv][s][c] = acc[s];
        }
        __syncthreads();
        // finalize h1: 128 threads, one per (sample, quad)
        if (tid < 128) {
            int s = tid >> 4, q = tid & 15;
            float4 a = red[0][s][q], b = red[1][s][q];
            float4 d = red[2][s][q], e = red[3][s][q];
            float4 sum = make_float4(a.x+b.x+d.x+e.x, a.y+b.y+d.y+e.y,
                                     a.z+b.z+d.z+e.z, a.w+b.w+d.w+e.w);
            ((float4*)h1s)[s * 16 + q] = gelu4(sum);
        }
        __syncthreads();

        // ---- layer 2: each thread reduces 4 hh-rows ----
        #pragma unroll
        for (int s = 0; s < 8; ++s) acc[s] = make_float4(0.f, 0.f, 0.f, 0.f);
        #pragma unroll
        for (int j = 0; j < 4; ++j) {
            const int hh = grp * 4 + j;
            float4 wv4 = L2[hh * 16 + c];
            #pragma unroll
            for (int s = 0; s < 8; ++s) {
                float hv = h1s[s][hh];
                acc[s].x = fmaf(hv, wv4.x, acc[s].x);
                acc[s].y = fmaf(hv, wv4.y, acc[s].y);
                acc[s].z = fmaf(hv, wv4.z, acc[s].z);
                acc[s].w = fmaf(hv, wv4.w, acc[s].w);
            }
        }
        #pragma unroll
        for (int s = 0; s < 8; ++s) {
            acc[s].x += __shfl_xor(acc[s].x, 16); acc[s].y += __shfl_xor(acc[s].y, 16);
            acc[s].z += __shfl_xor(acc[s].z, 16); acc[s].w += __shfl_xor(acc[s].w, 16);
            acc[s].x += __shfl_xor(acc[s].x, 32); acc[s].y += __shfl_xor(acc[s].y, 32);
            acc[s].z += __shfl_xor(acc[s].z, 32); acc[s].w += __shfl_xor(acc[s].w, 32);
        }
        if ((tid & 63) < 16) {
            #pragma unroll
            for (int s = 0; s < 8; ++s) red[wv][s][c] = acc[s];
        }
        __syncthreads();
        // finalize: h2 = gelu(sum), dot with l3, sigmoid
        if (tid < 128) {
            int s = tid >> 4, q = tid & 15;
            float4 a = red[0][s][q], b = red[1][s][q];
            float4 d = red[2][s][q], e = red[3][s][q];
            float4 h2 = gelu4(make_float4(a.x+b.x+d.x+e.x, a.y+b.y+d.y+e.y,
                                          a.z+b.z+d.z+e.z, a.w+b.w+d.w+e.w));
            float4 l3v = L3[q];
            float dot = h2.x*l3v.x + h2.y*l3v.y + h2.z*l3v.z + h2.w*l3v.w;
            dot += __shfl_xor(dot, 1);
            dot += __shfl_xor(dot, 2);
            dot += __shfl_xor(dot, 4);
            dot += __shfl_xor(dot, 8);
            if (q == 0 && s < S) out[sidx[s]] = 1.f / (1.f + expf(-dot));
        }
    }
}

extern "C" void kernel_launch(void* const* d_in, const int* in_sizes, int n_in,
                              void* d_out, int out_size, void* d_ws, size_t ws_size,
                              hipStream_t stream) {
    const float* x        = (const float*)d_in[0];
    const int*   task_ids = (const int*)  d_in[1];
    const float* l1_emb   = (const float*)d_in[2];
    const float* l2_emb   = (const float*)d_in[3];
    const float* l3_emb   = (const float*)d_in[4];
    float*       out      = (float*)d_out;

    int* ws      = (int*)d_ws;
    int* counts  = ws;
    int* offsets = ws + 1024;
    int* cursor  = ws + 2048;
    int* order   = ws + 3072;

    zero_counts   <<<4, 256, 0, stream>>>(counts, cursor);
    hist_kernel   <<<BATCH / 256, 256, 0, stream>>>(task_ids, counts);
    scan1024      <<<1, 1024, 0, stream>>>(counts, offsets);
    scatter_kernel<<<BATCH / 256, 256, 0, stream>>>(task_ids, offsets, cursor, order);
    mlp_task      <<<NTASK, 256, 0, stream>>>(x, order, counts, offsets,
                                              l1_emb, l2_emb, l3_emb, out);
}